// Round 14
// baseline (367.727 us; speedup 1.0000x reference)
//
#include <hip/hip_runtime.h>
#include <hip/hip_bf16.h>

#define BATCH 8
#define CGUID 3
#define CFEAT 128
#define IMH 224
#define IMW 224
#define NPTS 2048
#define HWSZ (IMH * IMW)

#define TILES 16          // NPTS / 128
#define NPAIR 136         // TILES*(TILES+1)/2
#define BM 128
#define BK 64
#define LDT 72            // padded LDS row stride in bf16 elems

typedef __attribute__((ext_vector_type(8))) short bf16x8;
typedef __attribute__((ext_vector_type(4))) float f32x4;

__device__ __forceinline__ ushort f2bf(float f) {
  unsigned x = __float_as_uint(f);
  unsigned r = (x + 0x7fffu + ((x >> 16) & 1u)) >> 16;   // round-to-nearest-even
  return (ushort)r;
}
__device__ __forceinline__ float bf2f(ushort u) {
  return __uint_as_float(((unsigned)u) << 16);
}

// ---------------------------------------------------------------------------
// Kernel 1: deep-ILP gather. Thread = (point, 8-channel segment):
// 8 INDEPENDENT stride-HWSZ loads in flight per thread, 1024 blocks
// (~64 outstanding loads/SIMD vs R11's ~16 -> latency-bound model collapses).
// Consecutive 16 threads = one point -> selF row writes are 16B/lane
// coalesced. sq-norm via 16-lane shuffle reduce; seg==0 lane fetches
// guidance and writes g4. Zeroes out[0].
// ---------------------------------------------------------------------------
__global__ __launch_bounds__(256) void gather_kernel(
    const float* __restrict__ guidance, const float* __restrict__ features,
    const int* __restrict__ coords,
    ushort* __restrict__ selF, float4* __restrict__ g4, float* __restrict__ out)
{
  if (blockIdx.x == 0 && threadIdx.x == 0) out[0] = 0.0f;

  int tid = blockIdx.x * 256 + threadIdx.x;
  int pid = tid >> 4;                      // 0 .. B*NPTS-1
  int seg = tid & 15;                      // 8-channel segment
  int b = pid >> 11;
  int n = pid & (NPTS - 1);

  int y = coords[n];
  int x = coords[NPTS + n];
  int lin = y * IMW + x;

  const float* fb = features + ((size_t)b * CFEAT + seg * 8) * HWSZ + lin;

  float v[8];
  #pragma unroll
  for (int k = 0; k < 8; ++k) v[k] = fb[(size_t)k * HWSZ];   // 8 loads in flight

  ushort u[8];
  float s = 0.0f;
  #pragma unroll
  for (int k = 0; k < 8; ++k) {
    u[k] = f2bf(v[k]);
    float fv = bf2f(u[k]);
    s += fv * fv;
  }

  int4 o;
  o.x = (int)((unsigned)u[0] | ((unsigned)u[1] << 16));
  o.y = (int)((unsigned)u[2] | ((unsigned)u[3] << 16));
  o.z = (int)((unsigned)u[4] | ((unsigned)u[5] << 16));
  o.w = (int)((unsigned)u[6] | ((unsigned)u[7] << 16));
  *(int4*)(selF + (size_t)pid * CFEAT + seg * 8) = o;

  // reduce sq-norm across the 16 segments of this point (consecutive lanes)
  #pragma unroll
  for (int ofs = 1; ofs < 16; ofs <<= 1) s += __shfl_xor(s, ofs);

  if (seg == 0) {
    const float* gb = guidance + (size_t)b * CGUID * HWSZ + lin;
    g4[pid] = make_float4(gb[0], gb[HWSZ], gb[2 * HWSZ], s);
  }
}

// ---------------------------------------------------------------------------
// Kernel 2: per (b, tile-pair ti<=tj): 128x128 Gram block via MFMA, fused
// sim-kernel epilogue, block partial sum -> atomicAdd (off-diag doubled).
// Normalized coords computed inline from the raw coords input.
// ---------------------------------------------------------------------------
__global__ __launch_bounds__(256) void crf_kernel(
    const ushort* __restrict__ selF, const float4* __restrict__ g4,
    const int* __restrict__ coords, float* __restrict__ out)
{
  __shared__ ushort As[BM * LDT];
  __shared__ ushort Bs[BM * LDT];
  __shared__ float4 egN[BM], egM[BM];
  __shared__ float2 ecN[BM], ecM[BM];
  __shared__ float red[4];

  int b = blockIdx.x / NPAIR;
  int p = blockIdx.x % NPAIR;
  int ti = 0, rem = p;
  while (rem >= TILES - ti) { rem -= TILES - ti; ++ti; }
  int tj = ti + rem;
  int nb0 = ti * BM, mb0 = tj * BM;

  int t = threadIdx.x;
  int lane = t & 63, wid = t >> 6;
  int wr = wid >> 1, wc = wid & 1;              // 2x2 waves -> 64x64 each

  // stage epilogue side-data (coords normalized inline)
  if (t < BM) {
    egN[t] = g4[b * NPTS + nb0 + t];
    ecN[t] = make_float2((float)coords[nb0 + t] / 224.0f,
                         (float)coords[NPTS + nb0 + t] / 224.0f);
  } else {
    int q = t - BM;
    egM[q] = g4[b * NPTS + mb0 + q];
    ecM[q] = make_float2((float)coords[mb0 + q] / 224.0f,
                         (float)coords[NPTS + mb0 + q] / 224.0f);
  }

  f32x4 acc[4][4];
  #pragma unroll
  for (int i = 0; i < 4; ++i)
    #pragma unroll
    for (int j = 0; j < 4; ++j) acc[i][j] = (f32x4)0.f;

  const ushort* SA = selF + ((size_t)b * NPTS + nb0) * CFEAT;
  const ushort* SB = selF + ((size_t)b * NPTS + mb0) * CFEAT;

  for (int kk = 0; kk < 2; ++kk) {
    __syncthreads();
    #pragma unroll
    for (int pass = 0; pass < 4; ++pass) {
      int idx = t + pass * 256;
      int row = idx >> 3, q = idx & 7;          // 8 int4 per 64-elem row-half
      int4 va = *(const int4*)(SA + (size_t)row * CFEAT + kk * BK + q * 8);
      *(int4*)(&As[row * LDT + q * 8]) = va;
      int4 vb = *(const int4*)(SB + (size_t)row * CFEAT + kk * BK + q * 8);
      *(int4*)(&Bs[row * LDT + q * 8]) = vb;
    }
    __syncthreads();
    #pragma unroll
    for (int k2 = 0; k2 < 2; ++k2) {
      int kb = k2 * 32 + (lane >> 4) * 8;       // bf16 offset within row
      bf16x8 a[4], bv[4];
      #pragma unroll
      for (int i = 0; i < 4; ++i)
        a[i] = *(const bf16x8*)(&As[(wr * 64 + i * 16 + (lane & 15)) * LDT + kb]);
      #pragma unroll
      for (int j = 0; j < 4; ++j)
        bv[j] = *(const bf16x8*)(&Bs[(wc * 64 + j * 16 + (lane & 15)) * LDT + kb]);
      #pragma unroll
      for (int i = 0; i < 4; ++i)
        #pragma unroll
        for (int j = 0; j < 4; ++j)
          acc[i][j] = __builtin_amdgcn_mfma_f32_16x16x32_bf16(a[i], bv[j], acc[i][j], 0, 0, 0);
    }
  }

  // epilogue: C/D layout col=lane&15, row=(lane>>4)*4+r
  float sum = 0.f;
  int mlo = lane & 15, nhi = lane >> 4;
  #pragma unroll
  for (int i = 0; i < 4; ++i) {
    #pragma unroll
    for (int r = 0; r < 4; ++r) {
      int n = wr * 64 + i * 16 + nhi * 4 + r;
      float4 gn = egN[n];
      float2 cn = ecN[n];
      #pragma unroll
      for (int j = 0; j < 4; ++j) {
        int m = wc * 64 + j * 16 + mlo;
        float4 gm = egM[m];
        float2 cm = ecM[m];
        float df = gn.w + gm.w - 2.0f * acc[i][j][r];
        df = fmaxf(df, 0.0f);
        float d0 = gn.x - gm.x, d1 = gn.y - gm.y, d2 = gn.z - gm.z;
        float dg = d0 * d0 + d1 * d1 + d2 * d2;
        float dy = cn.x - cm.x, dx = cn.y - cm.y;
        float dc = dy * dy + dx * dx;
        float sim = 10.0f * __expf(-5.0f * dc - 3.3333333f * dg)
                  +  3.0f * __expf(-100.0f * dc);
        sum += df * sim;
      }
    }
  }

  #pragma unroll
  for (int o = 32; o > 0; o >>= 1) sum += __shfl_down(sum, o);
  if (lane == 0) red[wid] = sum;
  __syncthreads();
  if (t == 0) {
    float tot = red[0] + red[1] + red[2] + red[3];
    float factor = (ti == tj ? 1.0f : 2.0f) * (1.0f / (8.0f * 2048.0f * 2048.0f));
    atomicAdd(out, tot * factor);
  }
}

extern "C" void kernel_launch(void* const* d_in, const int* in_sizes, int n_in,
                              void* d_out, int out_size, void* d_ws, size_t ws_size,
                              hipStream_t stream) {
  const float* guidance = (const float*)d_in[0];
  const float* features = (const float*)d_in[1];
  const int*   coords   = (const int*)d_in[2];
  float* out = (float*)d_out;

  char* ws = (char*)d_ws;
  size_t off = 0;
  ushort* selF  = (ushort*)(ws + off); off += (size_t)BATCH * NPTS * CFEAT * 2; // 4 MiB
  ushort* selF2 = (ushort*)(ws + off); off += (size_t)BATCH * NPTS * CFEAT * 2; // 4 MiB
  float4* g4    = (float4*)(ws + off); off += (size_t)BATCH * NPTS * 16;        // 256 KiB
  float4* g42   = (float4*)(ws + off); off += (size_t)BATCH * NPTS * 16;        // 256 KiB
  float*  dummy = (float*) (ws + off); off += 64;

  // Pipeline A (real output) + duplicate pipeline B (into dummy):
  // dur = floor + 2*ours -> with next round's single pipeline this
  // decomposes floor vs ours exactly.
  gather_kernel<<<BATCH * NPTS * 16 / 256, 256, 0, stream>>>(
      guidance, features, coords, selF, g4, out);
  gather_kernel<<<BATCH * NPTS * 16 / 256, 256, 0, stream>>>(
      guidance, features, coords, selF2, g42, dummy);
  crf_kernel<<<BATCH * NPAIR, 256, 0, stream>>>(selF, g4, coords, out);
  crf_kernel<<<BATCH * NPAIR, 256, 0, stream>>>(selF2, g42, coords, dummy);
}